// Round 2
// baseline (588.699 us; speedup 1.0000x reference)
//
#include <hip/hip_runtime.h>

#define EMB 64
#define HEADS 2
#define NUM_BOND 5
#define NEG_SLOPE 0.2f

// monotone float <-> uint mapping for atomicMax on floats
__device__ __forceinline__ unsigned fmap(float x){
    unsigned b = __float_as_uint(x);
    return (b & 0x80000000u) ? ~b : (b | 0x80000000u);
}
__device__ __forceinline__ float funmap(unsigned u){
    unsigned b = (u & 0x80000000u) ? (u & 0x7FFFFFFFu) : ~u;
    return __uint_as_float(b);
}

// consts[2*b+h] = sum_c W_edge[b, h*64+c] * att_j[h,c]
// consts[10+h]  = sum_c b_edge[h*64+c]    * att_j[h,c]
__global__ void k_setup(const float* __restrict__ W_edge, const float* __restrict__ b_edge,
                        const float* __restrict__ att, float* __restrict__ consts){
    int t = threadIdx.x;
    if (t < 12){
        int h = t & 1;
        const float* aj = att + h*2*EMB + EMB;   // att[0][h][64..127]
        float s = 0.f;
        if (t < 10){
            int b = t >> 1;
            for (int c = 0; c < EMB; c++) s += W_edge[b*(HEADS*EMB) + h*EMB + c] * aj[c];
        } else {
            for (int c = 0; c < EMB; c++) s += b_edge[h*EMB + c] * aj[c];
        }
        consts[t] = s;
    }
}

// one wave per node: h[n,:,:] = x[n]@W_lin + b_lin ; a_i[n,h]=h·att_i ; a_jn[n,h]=h·att_j
__global__ __launch_bounds__(256) void k_node(const float* __restrict__ x,
        const float* __restrict__ W_lin, const float* __restrict__ b_lin,
        const float* __restrict__ att,
        float* __restrict__ hbuf, float* __restrict__ a_i, float* __restrict__ a_jn, int N){
    __shared__ float WL[EMB*HEADS*EMB];          // 64*128 floats = 32 KB
    int t = threadIdx.x;
    for (int i = t; i < EMB*HEADS*EMB; i += 256) WL[i] = W_lin[i];
    __syncthreads();
    int wid = t >> 6, lane = t & 63;
    for (int n = blockIdx.x*4 + wid; n < N; n += gridDim.x*4){
        float xv = x[(size_t)n*EMB + lane];
        float acc0 = b_lin[lane], acc1 = b_lin[64 + lane];
        #pragma unroll 8
        for (int k = 0; k < EMB; k++){
            float xk = __shfl(xv, k);
            acc0 += xk * WL[k*128 + lane];
            acc1 += xk * WL[k*128 + 64 + lane];
        }
        hbuf[(size_t)n*128 + lane]      = acc0;
        hbuf[(size_t)n*128 + 64 + lane] = acc1;
        float p0 = acc0 * att[lane];         // att_i head0
        float p1 = acc1 * att[128 + lane];   // att_i head1
        float q0 = acc0 * att[64 + lane];    // att_j head0
        float q1 = acc1 * att[192 + lane];   // att_j head1
        for (int off = 32; off; off >>= 1){
            p0 += __shfl_xor(p0, off);
            p1 += __shfl_xor(p1, off);
            q0 += __shfl_xor(q0, off);
            q1 += __shfl_xor(q1, off);
        }
        if (lane == 0){
            a_i[n*2]    = p0; a_i[n*2+1]  = p1;
            a_jn[n*2]   = q0; a_jn[n*2+1] = q1;
        }
    }
}

// one thread per edge: alpha = lrelu(a_i[src]+a_jn[dst]+aje); atomicMax amax[src]
__global__ __launch_bounds__(256) void k_alpha(const int* __restrict__ ei,
        const float* __restrict__ edge_attr,
        const float* __restrict__ a_i, const float* __restrict__ a_jn,
        const float* __restrict__ consts,
        unsigned* __restrict__ amax, int E){
    int e = blockIdx.x*256 + threadIdx.x;
    if (e >= E) return;
    int s = ei[e], d = ei[E + e];
    float ea[NUM_BOND];
    #pragma unroll
    for (int b = 0; b < NUM_BOND; b++) ea[b] = edge_attr[(size_t)e*NUM_BOND + b];
    #pragma unroll
    for (int h = 0; h < HEADS; h++){
        float aje = consts[10 + h];
        #pragma unroll
        for (int b = 0; b < NUM_BOND; b++) aje += ea[b] * consts[2*b + h];
        float a = a_i[s*2 + h] + a_jn[d*2 + h] + aje;
        a = (a >= 0.f) ? a : NEG_SLOPE * a;
        atomicMax(amax + s*2 + h, fmap(a));
    }
}

// one wave per edge: recompute alpha, e=exp(alpha-amax); denom += e; acc[src] += e*(h[dst]+ee)
__global__ __launch_bounds__(256) void k_msg(const int* __restrict__ ei,
        const float* __restrict__ edge_attr,
        const float* __restrict__ W_edge, const float* __restrict__ b_edge,
        const float* __restrict__ hbuf,
        const float* __restrict__ a_i, const float* __restrict__ a_jn,
        const float* __restrict__ consts, const unsigned* __restrict__ amax,
        float* __restrict__ denom, float* __restrict__ acc, int E){
    __shared__ float WE[NUM_BOND*128];
    __shared__ float BE[128];
    __shared__ float CK[16];
    int t = threadIdx.x;
    for (int i = t; i < NUM_BOND*128; i += 256) WE[i] = W_edge[i];
    if (t < 128) BE[t] = b_edge[t];
    if (t < 16)  CK[t] = consts[t];
    __syncthreads();
    int wid = t >> 6, lane = t & 63;
    for (int e = blockIdx.x*4 + wid; e < E; e += gridDim.x*4){
        int s = ei[e], d = ei[E + e];
        float ea[NUM_BOND];
        #pragma unroll
        for (int b = 0; b < NUM_BOND; b++) ea[b] = edge_attr[(size_t)e*NUM_BOND + b];
        // recompute alpha per head (lanes redundantly compute; cheap VALU)
        float aje0 = CK[10], aje1 = CK[11];
        #pragma unroll
        for (int b = 0; b < NUM_BOND; b++){
            aje0 += ea[b] * CK[2*b];
            aje1 += ea[b] * CK[2*b + 1];
        }
        float al0 = a_i[s*2]     + a_jn[d*2]     + aje0;
        float al1 = a_i[s*2 + 1] + a_jn[d*2 + 1] + aje1;
        al0 = (al0 >= 0.f) ? al0 : NEG_SLOPE * al0;
        al1 = (al1 >= 0.f) ? al1 : NEG_SLOPE * al1;
        float e0 = __expf(al0 - funmap(amax[s*2]));
        float e1 = __expf(al1 - funmap(amax[s*2 + 1]));
        if (lane == 0){
            atomicAdd(denom + s*2,     e0);
            atomicAdd(denom + s*2 + 1, e1);
        }
        float ee0 = BE[lane], ee1 = BE[64 + lane];
        #pragma unroll
        for (int b = 0; b < NUM_BOND; b++){
            ee0 += ea[b] * WE[b*128 + lane];
            ee1 += ea[b] * WE[b*128 + 64 + lane];
        }
        float m0 = (hbuf[(size_t)d*128 + lane]      + ee0) * e0;
        float m1 = (hbuf[(size_t)d*128 + 64 + lane] + ee1) * e1;
        atomicAdd(acc + (size_t)s*128 + lane,      m0);
        atomicAdd(acc + (size_t)s*128 + 64 + lane, m1);
    }
}

// per (node, channel): out = mean over heads of acc/denom + bias
__global__ __launch_bounds__(256) void k_final(const float* __restrict__ acc,
        const float* __restrict__ denom, const float* __restrict__ bias,
        float* __restrict__ out, int N){
    int i = blockIdx.x*256 + threadIdx.x;
    if (i >= N*EMB) return;
    int n = i >> 6, c = i & 63;
    float o0 = acc[(size_t)n*128 + c]      / (denom[n*2]     + 1e-16f);
    float o1 = acc[(size_t)n*128 + 64 + c] / (denom[n*2 + 1] + 1e-16f);
    out[i] = 0.5f*(o0 + o1) + bias[c];
}

extern "C" void kernel_launch(void* const* d_in, const int* in_sizes, int n_in,
                              void* d_out, int out_size, void* d_ws, size_t ws_size,
                              hipStream_t stream){
    const float* x         = (const float*)d_in[0];
    const int*   ei        = (const int*)d_in[1];      // int32 [2][E]
    const float* edge_attr = (const float*)d_in[2];
    const float* W_lin     = (const float*)d_in[3];
    const float* b_lin     = (const float*)d_in[4];
    const float* W_edge    = (const float*)d_in[5];
    const float* b_edge    = (const float*)d_in[6];
    const float* att       = (const float*)d_in[7];
    const float* bias      = (const float*)d_in[8];
    int N = in_sizes[0] / EMB;
    int E = in_sizes[2] / NUM_BOND;

    float* ws    = (float*)d_ws;
    float* acc   = ws;                                  // N*128
    float* denom = acc + (size_t)N*128;                 // N*2
    unsigned* amax = (unsigned*)(denom + (size_t)N*2);  // N*2
    float* a_i   = (float*)(amax + (size_t)N*2);        // N*2
    float* a_jn  = a_i + (size_t)N*2;                   // N*2
    float* hbuf  = a_jn + (size_t)N*2;                  // N*128
    float* consts= hbuf + (size_t)N*128;                // 16

    // zero acc + denom + amax (amax: 0 maps below any real float)
    hipMemsetAsync(acc, 0, (size_t)(N*128 + N*4)*sizeof(float), stream);

    k_setup<<<1, 64, 0, stream>>>(W_edge, b_edge, att, consts);
    k_node <<<2048, 256, 0, stream>>>(x, W_lin, b_lin, att, hbuf, a_i, a_jn, N);
    k_alpha<<<(E + 255)/256, 256, 0, stream>>>(ei, edge_attr, a_i, a_jn, consts, amax, E);
    k_msg  <<<8192, 256, 0, stream>>>(ei, edge_attr, W_edge, b_edge, hbuf, a_i, a_jn, consts, amax, denom, acc, E);
    k_final<<<((size_t)N*EMB + 255)/256, 256, 0, stream>>>(acc, denom, bias, (float*)d_out, N);
}

// Round 3
// 384.834 us; speedup vs baseline: 1.5297x; 1.5297x over previous
//
#include <hip/hip_runtime.h>

#define EMB 64
#define HEADS 2
#define NUM_BOND 5
#define NEG_SLOPE 0.2f

// consts[2*b+h] = sum_c W_edge[b, h*64+c] * att_j[h,c]
// consts[10+h]  = sum_c b_edge[h*64+c]    * att_j[h,c]
__global__ void k_setup(const float* __restrict__ W_edge, const float* __restrict__ b_edge,
                        const float* __restrict__ att, float* __restrict__ consts){
    int t = threadIdx.x;
    if (t < 12){
        int h = t & 1;
        const float* aj = att + h*2*EMB + EMB;   // att[0][h][64..127]
        float s = 0.f;
        if (t < 10){
            int b = t >> 1;
            for (int c = 0; c < EMB; c++) s += W_edge[b*(HEADS*EMB) + h*EMB + c] * aj[c];
        } else {
            for (int c = 0; c < EMB; c++) s += b_edge[h*EMB + c] * aj[c];
        }
        consts[t] = s;
    }
}

// one wave per node: h[n,:,:] = x[n]@W_lin + b_lin ; a_i[n,h]=h·att_i ; a_jn[n,h]=h·att_j
__global__ __launch_bounds__(256) void k_node(const float* __restrict__ x,
        const float* __restrict__ W_lin, const float* __restrict__ b_lin,
        const float* __restrict__ att,
        float* __restrict__ hbuf, float* __restrict__ a_i, float* __restrict__ a_jn, int N){
    __shared__ float WL[EMB*HEADS*EMB];          // 32 KB
    int t = threadIdx.x;
    for (int i = t; i < EMB*HEADS*EMB; i += 256) WL[i] = W_lin[i];
    __syncthreads();
    int wid = t >> 6, lane = t & 63;
    for (int n = blockIdx.x*4 + wid; n < N; n += gridDim.x*4){
        float xv = x[(size_t)n*EMB + lane];
        float acc0 = b_lin[lane], acc1 = b_lin[64 + lane];
        #pragma unroll 8
        for (int k = 0; k < EMB; k++){
            float xk = __shfl(xv, k);
            acc0 += xk * WL[k*128 + lane];
            acc1 += xk * WL[k*128 + 64 + lane];
        }
        hbuf[(size_t)n*128 + lane]      = acc0;
        hbuf[(size_t)n*128 + 64 + lane] = acc1;
        float p0 = acc0 * att[lane];         // att_i head0
        float p1 = acc1 * att[128 + lane];   // att_i head1
        float q0 = acc0 * att[64 + lane];    // att_j head0
        float q1 = acc1 * att[192 + lane];   // att_j head1
        for (int off = 32; off; off >>= 1){
            p0 += __shfl_xor(p0, off);
            p1 += __shfl_xor(p1, off);
            q0 += __shfl_xor(q0, off);
            q1 += __shfl_xor(q1, off);
        }
        if (lane == 0){
            a_i[n*2]    = p0; a_i[n*2+1]  = p1;
            a_jn[n*2]   = q0; a_jn[n*2+1] = q1;
        }
    }
}

__global__ __launch_bounds__(256) void k_hist(const int* __restrict__ ei,
        int* __restrict__ cnt, int E){
    int e = blockIdx.x*256 + threadIdx.x;
    if (e < E) atomicAdd(cnt + ei[e], 1);
}

// single block, 1024 threads: exclusive scan of cnt -> offsets (and cursor copy)
__global__ __launch_bounds__(1024) void k_scan(const int* __restrict__ cnt,
        int* __restrict__ offsets, int* __restrict__ cursor, int N){
    __shared__ int wsum[16];
    int t = threadIdx.x;
    int chunk = (N + 1023) >> 10;
    int lo = t * chunk; if (lo > N) lo = N;
    int hi = lo + chunk; if (hi > N) hi = N;
    int s = 0;
    for (int i = lo; i < hi; i++) s += cnt[i];
    int lane = t & 63, wid = t >> 6;
    int v = s;
    #pragma unroll
    for (int off = 1; off < 64; off <<= 1){
        int u = __shfl_up(v, off);
        if (lane >= off) v += u;
    }
    if (lane == 63) wsum[wid] = v;
    __syncthreads();
    if (t < 16){
        int w = wsum[t];
        #pragma unroll
        for (int off = 1; off < 16; off <<= 1){
            int u = __shfl_up(w, off);
            if (t >= off) w += u;
        }
        wsum[t] = w;
    }
    __syncthreads();
    int run = (wid ? wsum[wid - 1] : 0) + (v - s);   // exclusive prefix for this thread
    for (int i = lo; i < hi; i++){
        offsets[i] = run;
        cursor[i]  = run;
        run += cnt[i];
    }
}

// counting-sort edges by src: record = {dst, ea0..4, aje0, aje1} (32 B)
__global__ __launch_bounds__(256) void k_scatter(const int* __restrict__ ei,
        const float* __restrict__ edge_attr, const float* __restrict__ consts,
        int* __restrict__ cursor, float4* __restrict__ rec, int E){
    __shared__ float CK[12];
    if (threadIdx.x < 12) CK[threadIdx.x] = consts[threadIdx.x];
    __syncthreads();
    int e = blockIdx.x*256 + threadIdx.x;
    if (e >= E) return;
    int s = ei[e], d = ei[E + e];
    float ea[NUM_BOND];
    #pragma unroll
    for (int b = 0; b < NUM_BOND; b++) ea[b] = edge_attr[(size_t)e*NUM_BOND + b];
    float aje0 = CK[10], aje1 = CK[11];
    #pragma unroll
    for (int b = 0; b < NUM_BOND; b++){
        aje0 += ea[b] * CK[2*b];
        aje1 += ea[b] * CK[2*b + 1];
    }
    int pos = atomicAdd(cursor + s, 1);
    rec[(size_t)pos*2]     = make_float4(__int_as_float(d), ea[0], ea[1], ea[2]);
    rec[(size_t)pos*2 + 1] = make_float4(ea[3], ea[4], aje0, aje1);
}

// one wave per node: walk CSR edge list, online softmax + accumulate in registers
__global__ __launch_bounds__(256) void k_gat(const float4* __restrict__ rec,
        const int* __restrict__ offsets, const int* __restrict__ cnt,
        const float* __restrict__ hbuf, const float* __restrict__ a_i,
        const float* __restrict__ a_jn,
        const float* __restrict__ W_edge, const float* __restrict__ b_edge,
        const float* __restrict__ bias, float* __restrict__ out, int N){
    __shared__ float WE[NUM_BOND*128];
    __shared__ float BE[128];
    int t = threadIdx.x;
    for (int i = t; i < NUM_BOND*128; i += 256) WE[i] = W_edge[i];
    if (t < 128) BE[t] = b_edge[t];
    __syncthreads();
    int wid = t >> 6, lane = t & 63;
    int n = blockIdx.x*4 + wid;
    if (n >= N) return;

    int start = offsets[n], deg = cnt[n];
    float ai0 = a_i[n*2], ai1 = a_i[n*2 + 1];
    float W0a = WE[lane],       W1a = WE[128 + lane], W2a = WE[256 + lane];
    float W3a = WE[384 + lane], W4a = WE[512 + lane];
    float W0b = WE[64 + lane],  W1b = WE[192 + lane], W2b = WE[320 + lane];
    float W3b = WE[448 + lane], W4b = WE[576 + lane];
    float be0 = BE[lane], be1 = BE[64 + lane];

    float m0 = -1e30f, m1 = -1e30f;
    float d0 = 0.f, d1 = 0.f, A0 = 0.f, A1 = 0.f;

    for (int k = 0; k < deg; k++){
        float4 ra = rec[(size_t)(start + k)*2];
        float4 rb = rec[(size_t)(start + k)*2 + 1];
        int dst = __float_as_int(ra.x);
        float hv0 = hbuf[(size_t)dst*128 + lane];
        float hv1 = hbuf[(size_t)dst*128 + 64 + lane];
        float aj0 = a_jn[dst*2], aj1 = a_jn[dst*2 + 1];
        float al0 = ai0 + aj0 + rb.z;
        float al1 = ai1 + aj1 + rb.w;
        al0 = (al0 >= 0.f) ? al0 : NEG_SLOPE * al0;
        al1 = (al1 >= 0.f) ? al1 : NEG_SLOPE * al1;
        float nm0 = fmaxf(m0, al0), nm1 = fmaxf(m1, al1);
        float sc0 = __expf(m0 - nm0), sc1 = __expf(m1 - nm1);
        float e0  = __expf(al0 - nm0), e1 = __expf(al1 - nm1);
        m0 = nm0; m1 = nm1;
        float ee0 = be0 + ra.y*W0a + ra.z*W1a + ra.w*W2a + rb.x*W3a + rb.y*W4a;
        float ee1 = be1 + ra.y*W0b + ra.z*W1b + ra.w*W2b + rb.x*W3b + rb.y*W4b;
        d0 = d0*sc0 + e0;
        d1 = d1*sc1 + e1;
        A0 = A0*sc0 + e0*(hv0 + ee0);
        A1 = A1*sc1 + e1*(hv1 + ee1);
    }
    out[(size_t)n*EMB + lane] = 0.5f*(A0/(d0 + 1e-16f) + A1/(d1 + 1e-16f)) + bias[lane];
}

extern "C" void kernel_launch(void* const* d_in, const int* in_sizes, int n_in,
                              void* d_out, int out_size, void* d_ws, size_t ws_size,
                              hipStream_t stream){
    const float* x         = (const float*)d_in[0];
    const int*   ei        = (const int*)d_in[1];      // int32 [2][E]
    const float* edge_attr = (const float*)d_in[2];
    const float* W_lin     = (const float*)d_in[3];
    const float* b_lin     = (const float*)d_in[4];
    const float* W_edge    = (const float*)d_in[5];
    const float* b_edge    = (const float*)d_in[6];
    const float* att       = (const float*)d_in[7];
    const float* bias      = (const float*)d_in[8];
    int N = in_sizes[0] / EMB;
    int E = in_sizes[2] / NUM_BOND;

    float* ws     = (float*)d_ws;
    float* hbuf   = ws;                                // N*128
    float* a_i    = hbuf + (size_t)N*128;              // N*2
    float* a_jn   = a_i + (size_t)N*2;                 // N*2
    float* consts = a_jn + (size_t)N*2;                // 16
    int*   cnt    = (int*)(consts + 16);               // N
    int*   offsets= cnt + N;                           // N
    int*   cursor = offsets + N;                       // N
    uintptr_t raddr = (uintptr_t)(cursor + N);
    raddr = (raddr + 15) & ~(uintptr_t)15;
    float4* rec   = (float4*)raddr;                    // E*2 float4 (32 B/edge)

    hipMemsetAsync(cnt, 0, (size_t)N*sizeof(int), stream);

    k_setup  <<<1, 64, 0, stream>>>(W_edge, b_edge, att, consts);
    k_node   <<<2048, 256, 0, stream>>>(x, W_lin, b_lin, att, hbuf, a_i, a_jn, N);
    k_hist   <<<(E + 255)/256, 256, 0, stream>>>(ei, cnt, E);
    k_scan   <<<1, 1024, 0, stream>>>(cnt, offsets, cursor, N);
    k_scatter<<<(E + 255)/256, 256, 0, stream>>>(ei, edge_attr, consts, cursor, rec, E);
    k_gat    <<<(N + 3)/4, 256, 0, stream>>>(rec, offsets, cnt, hbuf, a_i, a_jn,
                                             W_edge, b_edge, bias, (float*)d_out, N);
}

// Round 4
// 378.228 us; speedup vs baseline: 1.5565x; 1.0175x over previous
//
#include <hip/hip_runtime.h>

#define EMB 64
#define HEADS 2
#define NUM_BOND 5
#define NEG_SLOPE 0.2f
#define LOG2E 1.44269504088896f

__device__ __forceinline__ unsigned bf16rne(float f){
    unsigned u = __float_as_uint(f);
    return (u + 0x7FFFu + ((u >> 16) & 1u)) >> 16;
}
__device__ __forceinline__ float bf16lo(unsigned p){ return __uint_as_float(p << 16); }
__device__ __forceinline__ float bf16hi(unsigned p){ return __uint_as_float(p & 0xFFFF0000u); }

// consts[2*b+h] = sum_c W_edge[b, h*64+c] * att_j[h,c]
// consts[10+h]  = sum_c b_edge[h*64+c]    * att_j[h,c]
__global__ void k_setup(const float* __restrict__ W_edge, const float* __restrict__ b_edge,
                        const float* __restrict__ att, float* __restrict__ consts){
    int t = threadIdx.x;
    if (t < 12){
        int h = t & 1;
        const float* aj = att + h*2*EMB + EMB;
        float s = 0.f;
        if (t < 10){
            int b = t >> 1;
            for (int c = 0; c < EMB; c++) s += W_edge[b*(HEADS*EMB) + h*EMB + c] * aj[c];
        } else {
            for (int c = 0; c < EMB; c++) s += b_edge[h*EMB + c] * aj[c];
        }
        consts[t] = s;
    }
}

// fused: src histogram + node transform. hb = packed bf16 {head0|head1<<16} per channel.
// a_i stored pre-scaled by LOG2E; a_jn stored raw.
__global__ __launch_bounds__(256) void k_node(const float* __restrict__ x,
        const float* __restrict__ W_lin, const float* __restrict__ b_lin,
        const float* __restrict__ att, const int* __restrict__ ei, int E,
        unsigned* __restrict__ hb, float* __restrict__ a_i, float* __restrict__ a_jn,
        int* __restrict__ cnt, int N){
    __shared__ float WL[EMB*HEADS*EMB];          // 32 KB
    int t = threadIdx.x;
    for (int e = blockIdx.x*256 + t; e < E; e += gridDim.x*256)
        atomicAdd(cnt + ei[e], 1);
    for (int i = t; i < EMB*HEADS*EMB; i += 256) WL[i] = W_lin[i];
    __syncthreads();
    int wid = t >> 6, lane = t & 63;
    for (int n = blockIdx.x*4 + wid; n < N; n += gridDim.x*4){
        float xv = x[(size_t)n*EMB + lane];
        float acc0 = b_lin[lane], acc1 = b_lin[64 + lane];
        #pragma unroll 8
        for (int k = 0; k < EMB; k++){
            float xk = __shfl(xv, k);
            acc0 += xk * WL[k*128 + lane];
            acc1 += xk * WL[k*128 + 64 + lane];
        }
        hb[(size_t)n*EMB + lane] = bf16rne(acc0) | (bf16rne(acc1) << 16);
        float p0 = acc0 * att[lane];         // att_i head0
        float p1 = acc1 * att[128 + lane];   // att_i head1
        float q0 = acc0 * att[64 + lane];    // att_j head0
        float q1 = acc1 * att[192 + lane];   // att_j head1
        for (int off = 32; off; off >>= 1){
            p0 += __shfl_xor(p0, off);
            p1 += __shfl_xor(p1, off);
            q0 += __shfl_xor(q0, off);
            q1 += __shfl_xor(q1, off);
        }
        if (lane == 0){
            a_i[n*2]    = p0 * LOG2E; a_i[n*2+1]  = p1 * LOG2E;
            a_jn[n*2]   = q0;         a_jn[n*2+1] = q1;
        }
    }
}

// single block, 1024 threads: exclusive scan of cnt -> offsets (and cursor copy)
__global__ __launch_bounds__(1024) void k_scan(const int* __restrict__ cnt,
        int* __restrict__ offsets, int* __restrict__ cursor, int N){
    __shared__ int wsum[16];
    int t = threadIdx.x;
    int chunk = (N + 1023) >> 10;
    int lo = t * chunk; if (lo > N) lo = N;
    int hi = lo + chunk; if (hi > N) hi = N;
    int s = 0;
    for (int i = lo; i < hi; i++) s += cnt[i];
    int lane = t & 63, wid = t >> 6;
    int v = s;
    #pragma unroll
    for (int off = 1; off < 64; off <<= 1){
        int u = __shfl_up(v, off);
        if (lane >= off) v += u;
    }
    if (lane == 63) wsum[wid] = v;
    __syncthreads();
    if (t < 16){
        int w = wsum[t];
        #pragma unroll
        for (int off = 1; off < 16; off <<= 1){
            int u = __shfl_up(w, off);
            if (t >= off) w += u;
        }
        wsum[t] = w;
    }
    __syncthreads();
    int run = (wid ? wsum[wid - 1] : 0) + (v - s);
    for (int i = lo; i < hi; i++){
        offsets[i] = run;
        cursor[i]  = run;
        run += cnt[i];
    }
}

// counting-sort edges by src. record: {dst, ea0, ea1, ea2}, {ea3, ea4, c0, c1}
// c_h = (a_jn[dst,h] + aje_h) * LOG2E  (pre-scaled for exp2)
__global__ __launch_bounds__(256) void k_scatter(const int* __restrict__ ei,
        const float* __restrict__ edge_attr, const float* __restrict__ consts,
        const float* __restrict__ a_jn,
        int* __restrict__ cursor, float4* __restrict__ rec, int E){
    __shared__ float CK[12];
    if (threadIdx.x < 12) CK[threadIdx.x] = consts[threadIdx.x];
    __syncthreads();
    int e = blockIdx.x*256 + threadIdx.x;
    if (e >= E) return;
    int s = ei[e], d = ei[E + e];
    float ea[NUM_BOND];
    #pragma unroll
    for (int b = 0; b < NUM_BOND; b++) ea[b] = edge_attr[(size_t)e*NUM_BOND + b];
    float aje0 = CK[10], aje1 = CK[11];
    #pragma unroll
    for (int b = 0; b < NUM_BOND; b++){
        aje0 += ea[b] * CK[2*b];
        aje1 += ea[b] * CK[2*b + 1];
    }
    float c0 = (a_jn[d*2]     + aje0) * LOG2E;
    float c1 = (a_jn[d*2 + 1] + aje1) * LOG2E;
    int pos = atomicAdd(cursor + s, 1);
    rec[(size_t)pos*2]     = make_float4(__int_as_float(d), ea[0], ea[1], ea[2]);
    rec[(size_t)pos*2 + 1] = make_float4(ea[3], ea[4], c0, c1);
}

// one wave per node: walk CSR, online softmax in log2 domain, bf16 h gather,
// ee-term factored out: num = A + d*b_edge + sum_b eb[b]*W_edge[b]
__global__ __launch_bounds__(256) void k_gat(const float4* __restrict__ rec,
        const int* __restrict__ offsets, const int* __restrict__ cnt,
        const unsigned* __restrict__ hb, const float* __restrict__ a_i,
        const float* __restrict__ W_edge, const float* __restrict__ b_edge,
        const float* __restrict__ bias, float* __restrict__ out, int N){
    __shared__ float WE[NUM_BOND*128];
    __shared__ float BE[128];
    int t = threadIdx.x;
    for (int i = t; i < NUM_BOND*128; i += 256) WE[i] = W_edge[i];
    if (t < 128) BE[t] = b_edge[t];
    __syncthreads();
    int wid = t >> 6, lane = t & 63;
    int n = blockIdx.x*4 + wid;
    if (n >= N) return;

    int start = offsets[n], deg = cnt[n];
    float ai0 = a_i[n*2], ai1 = a_i[n*2 + 1];   // already *LOG2E

    float m0 = -1e30f, m1 = -1e30f;
    float d0 = 0.f, d1 = 0.f, A0 = 0.f, A1 = 0.f;
    float eb00=0.f, eb01=0.f, eb02=0.f, eb03=0.f, eb04=0.f;
    float eb10=0.f, eb11=0.f, eb12=0.f, eb13=0.f, eb14=0.f;

    float4 raN, rbN; unsigned hvN = 0;
    if (deg > 0){
        raN = rec[(size_t)start*2];
        rbN = rec[(size_t)start*2 + 1];
        hvN = hb[(size_t)__float_as_int(raN.x)*EMB + lane];
    }
    for (int k = 0; k < deg; k++){
        float4 ra = raN, rb = rbN; unsigned hv = hvN;
        if (k + 1 < deg){
            raN = rec[(size_t)(start + k + 1)*2];
            rbN = rec[(size_t)(start + k + 1)*2 + 1];
            hvN = hb[(size_t)__float_as_int(raN.x)*EMB + lane];
        }
        float al0 = ai0 + rb.z;                  // log2-domain logit
        float al1 = ai1 + rb.w;
        al0 = (al0 >= 0.f) ? al0 : NEG_SLOPE * al0;
        al1 = (al1 >= 0.f) ? al1 : NEG_SLOPE * al1;
        float hv0 = bf16lo(hv), hv1 = bf16hi(hv);
        // head 0 (branch is wave-uniform: al0 identical across lanes)
        if (al0 > m0){
            float sc = exp2f(m0 - al0);
            d0 = d0*sc + 1.f;
            A0 = fmaf(A0, sc, hv0);
            eb00 = fmaf(eb00, sc, ra.y); eb01 = fmaf(eb01, sc, ra.z);
            eb02 = fmaf(eb02, sc, ra.w); eb03 = fmaf(eb03, sc, rb.x);
            eb04 = fmaf(eb04, sc, rb.y);
            m0 = al0;
        } else {
            float e0 = exp2f(al0 - m0);
            d0 += e0;
            A0 = fmaf(e0, hv0, A0);
            eb00 = fmaf(e0, ra.y, eb00); eb01 = fmaf(e0, ra.z, eb01);
            eb02 = fmaf(e0, ra.w, eb02); eb03 = fmaf(e0, rb.x, eb03);
            eb04 = fmaf(e0, rb.y, eb04);
        }
        // head 1
        if (al1 > m1){
            float sc = exp2f(m1 - al1);
            d1 = d1*sc + 1.f;
            A1 = fmaf(A1, sc, hv1);
            eb10 = fmaf(eb10, sc, ra.y); eb11 = fmaf(eb11, sc, ra.z);
            eb12 = fmaf(eb12, sc, ra.w); eb13 = fmaf(eb13, sc, rb.x);
            eb14 = fmaf(eb14, sc, rb.y);
            m1 = al1;
        } else {
            float e1 = exp2f(al1 - m1);
            d1 += e1;
            A1 = fmaf(e1, hv1, A1);
            eb10 = fmaf(e1, ra.y, eb10); eb11 = fmaf(e1, ra.z, eb11);
            eb12 = fmaf(e1, ra.w, eb12); eb13 = fmaf(e1, rb.x, eb13);
            eb14 = fmaf(e1, rb.y, eb14);
        }
    }
    float num0 = fmaf(d0, BE[lane],      A0);
    float num1 = fmaf(d1, BE[64 + lane], A1);
    num0 = fmaf(eb00, WE[lane],            num0);
    num0 = fmaf(eb01, WE[128 + lane],      num0);
    num0 = fmaf(eb02, WE[256 + lane],      num0);
    num0 = fmaf(eb03, WE[384 + lane],      num0);
    num0 = fmaf(eb04, WE[512 + lane],      num0);
    num1 = fmaf(eb10, WE[64 + lane],       num1);
    num1 = fmaf(eb11, WE[192 + lane],      num1);
    num1 = fmaf(eb12, WE[320 + lane],      num1);
    num1 = fmaf(eb13, WE[448 + lane],      num1);
    num1 = fmaf(eb14, WE[576 + lane],      num1);
    out[(size_t)n*EMB + lane] = 0.5f*(num0/(d0 + 1e-16f) + num1/(d1 + 1e-16f)) + bias[lane];
}

extern "C" void kernel_launch(void* const* d_in, const int* in_sizes, int n_in,
                              void* d_out, int out_size, void* d_ws, size_t ws_size,
                              hipStream_t stream){
    const float* x         = (const float*)d_in[0];
    const int*   ei        = (const int*)d_in[1];      // int32 [2][E]
    const float* edge_attr = (const float*)d_in[2];
    const float* W_lin     = (const float*)d_in[3];
    const float* b_lin     = (const float*)d_in[4];
    const float* W_edge    = (const float*)d_in[5];
    const float* b_edge    = (const float*)d_in[6];
    const float* att       = (const float*)d_in[7];
    const float* bias      = (const float*)d_in[8];
    int N = in_sizes[0] / EMB;
    int E = in_sizes[2] / NUM_BOND;

    float* ws     = (float*)d_ws;
    unsigned* hb  = (unsigned*)ws;                     // N*64 packed bf16x2
    float* a_i    = (float*)(hb + (size_t)N*EMB);      // N*2
    float* a_jn   = a_i + (size_t)N*2;                 // N*2
    float* consts = a_jn + (size_t)N*2;                // 16
    int*   cnt    = (int*)(consts + 16);               // N
    int*   offsets= cnt + N;                           // N
    int*   cursor = offsets + N;                       // N
    uintptr_t raddr = (uintptr_t)(cursor + N);
    raddr = (raddr + 15) & ~(uintptr_t)15;
    float4* rec   = (float4*)raddr;                    // E*2 float4 (32 B/edge)

    hipMemsetAsync(cnt, 0, (size_t)N*sizeof(int), stream);

    k_setup  <<<1, 64, 0, stream>>>(W_edge, b_edge, att, consts);
    k_node   <<<2048, 256, 0, stream>>>(x, W_lin, b_lin, att, ei, E, hb, a_i, a_jn, cnt, N);
    k_scan   <<<1, 1024, 0, stream>>>(cnt, offsets, cursor, N);
    k_scatter<<<(E + 255)/256, 256, 0, stream>>>(ei, edge_attr, consts, a_jn, cursor, rec, E);
    k_gat    <<<(N + 3)/4, 256, 0, stream>>>(rec, offsets, cnt, hb, a_i,
                                             W_edge, b_edge, bias, (float*)d_out, N);
}